// Round 1
// baseline (390.232 us; speedup 1.0000x reference)
//
#include <hip/hip_runtime.h>

#define IN_F   4096
#define OUT_F  16384
#define GROUP  128
#define BATCH  4

#define THREADS  128
#define CPT      4                      // columns per thread (one int4)
#define COL_TILE (THREADS * CPT)        // 512
#define NCT      (OUT_F / COL_TILE)     // 32 column tiles
#define NSEG     (IN_F / GROUP)         // 32 reduction segments (1 quant group each)

// out[b][j] = bias[j]  (d_out is re-poisoned 0xAA before every launch)
__global__ __launch_bounds__(256) void qlin_init(const float* __restrict__ bias,
                                                 float* __restrict__ out) {
    int j = blockIdx.x * 256 + threadIdx.x;          // float4 index, 0..4095
    float4 b = reinterpret_cast<const float4*>(bias)[j];
    float4* o = reinterpret_cast<float4*>(out);
    o[j]                 = b;
    o[j +     OUT_F / 4] = b;
    o[j + 2 * OUT_F / 4] = b;
    o[j + 3 * OUT_F / 4] = b;
}

__global__ __launch_bounds__(THREADS) void qlin_main(const float* __restrict__ x,
                                                     const int*   __restrict__ wq,
                                                     const float* __restrict__ scales,
                                                     float*       __restrict__ out) {
    __shared__ float xs[BATCH][GROUP];

    const int seg = blockIdx.y;   // quant group / 128-row segment
    const int ct  = blockIdx.x;   // column tile
    const int tid = threadIdx.x;

    // Stage this segment's x slice: 4 rows x 128 cols = 2 KB
    for (int f = tid; f < BATCH * GROUP; f += THREADS) {
        int b  = f >> 7;            // /GROUP
        int ii = f & (GROUP - 1);
        xs[b][ii] = x[b * IN_F + seg * GROUP + ii];
    }
    __syncthreads();

    const int j0 = ct * COL_TILE + tid * CPT;
    const int4* wp =
        reinterpret_cast<const int4*>(wq + (size_t)seg * GROUP * OUT_F + j0);

    float acc[BATCH][CPT];
#pragma unroll
    for (int b = 0; b < BATCH; ++b)
#pragma unroll
        for (int c = 0; c < CPT; ++c) acc[b][c] = 0.0f;

#pragma unroll 8
    for (int ii = 0; ii < GROUP; ++ii) {
        int4 w = wp[(size_t)ii * (OUT_F / 4)];
        float w0 = (float)w.x, w1 = (float)w.y, w2 = (float)w.z, w3 = (float)w.w;
#pragma unroll
        for (int b = 0; b < BATCH; ++b) {
            float xv = xs[b][ii];
            acc[b][0] += xv * w0;
            acc[b][1] += xv * w1;
            acc[b][2] += xv * w2;
            acc[b][3] += xv * w3;
        }
    }

    // Apply per-group scale once, then accumulate into out.
    float4 sc = *reinterpret_cast<const float4*>(scales + (size_t)seg * OUT_F + j0);
#pragma unroll
    for (int b = 0; b < BATCH; ++b) {
        float* op = out + b * OUT_F + j0;
        atomicAdd(op + 0, acc[b][0] * sc.x);
        atomicAdd(op + 1, acc[b][1] * sc.y);
        atomicAdd(op + 2, acc[b][2] * sc.z);
        atomicAdd(op + 3, acc[b][3] * sc.w);
    }
}

extern "C" void kernel_launch(void* const* d_in, const int* in_sizes, int n_in,
                              void* d_out, int out_size, void* d_ws, size_t ws_size,
                              hipStream_t stream) {
    const float* x      = (const float*)d_in[0];
    const int*   wq     = (const int*)d_in[1];
    const float* scales = (const float*)d_in[2];
    const float* bias   = (const float*)d_in[3];
    float*       out    = (float*)d_out;

    qlin_init<<<dim3(OUT_F / 4 / 256), 256, 0, stream>>>(bias, out);
    qlin_main<<<dim3(NCT, NSEG), THREADS, 0, stream>>>(x, wq, scales, out);
}